// Round 6
// baseline (74.207 us; speedup 1.0000x reference)
//
#include <hip/hip_runtime.h>

#define ROWS 64      // rows per block
#define TPB  192     // 3 waves: wave k handles matrix column k for all 64 rows
#define XDIM 99
#define NJ   26
#define LSTR 49      // LDS row stride in floats (odd -> strided access spreads banks)
#define CHW  48      // chunk width in floats (2 chunks cover floats 0..95)
#define OUTW 78      // output floats per row

__device__ __forceinline__ void rodrigues(float ax, float ay, float az, float* R) {
    const float EPS = 1.1920928955078125e-07f;   // np.finfo(np.float32).eps
    float t = sqrtf(ax*ax + ay*ay + az*az);
    float inv = 1.0f / (t + EPS);
    float r0 = ax*inv, r1 = ay*inv, r2 = az*inv;
    float s = __sinf(t);
    float c = __cosf(t);
    float omc = 1.0f - c;
    float r00 = r0*r0, r11 = r1*r1, r22 = r2*r2;
    float r01 = r0*r1, r02 = r0*r2, r12 = r1*r2;
    R[0] = 1.0f - omc*(r11 + r22);
    R[1] = -s*r2 + omc*r01;
    R[2] =  s*r1 + omc*r02;
    R[3] =  s*r2 + omc*r01;
    R[4] = 1.0f - omc*(r00 + r22);
    R[5] = -s*r0 + omc*r12;
    R[6] = -s*r1 + omc*r02;
    R[7] =  s*r0 + omc*r12;
    R[8] = 1.0f - omc*(r00 + r11);
}

__global__ __launch_bounds__(TPB, 8) void skel_fk(const float* __restrict__ x,
                                                  const float* __restrict__ off,
                                                  float* __restrict__ out) {
    __shared__ float buf[ROWS * LSTR];           // 12544 B -> 10 blocks/CU (wave-capped)
    const int t = threadIdx.x;
    const int row0 = blockIdx.x * ROWS;
    const int r = t & 63;                        // row owned in compute phases
    const int k = t >> 6;                        // matrix column (wave-uniform)

    // staging decomposition: 192 = 4*48, so thread t always loads column c0 of
    // rows r0, r0+4, ..., r0+60 — zero per-iteration division, linear bumps.
    const int c0 = t % CHW;
    const int r0 = t / CHW;

    // slot tables (slot 0 = hip, slots 1..25 follow ORDER)
    constexpr int OFF_IDX[NJ] = {0,1,2,3,4,6,7,8,9,11,12,13,14,15,16,17,18,19,20,22,24,25,26,27,28,30};
    constexpr int PAR[NJ]     = {-1,0,1,2,3,0,5,6,7,0,9,10,11,12,10,14,15,16,17,17,10,20,21,22,23,23};

    float ac[NJ][3];   // column k of ang[slot]; compile-time indices -> registers
    float pp[NJ];      // component k of pos[slot]; per-phase liveness (<=14 live)

    // ---- stage chunk A: floats [0..48) of each row ----
    #pragma unroll
    for (int j = 0; j < 16; ++j) {
        int rr = r0 + 4*j;
        buf[rr*LSTR + c0] = x[(long long)(row0 + rr)*XDIM + c0];
    }
    __syncthreads();

    // ---- compute slots 0..12 (inputs wholly in chunk A; no LDS writes) ----
    {
        const float* row = &buf[r*LSTR];
        float R[9];
        rodrigues(row[3], row[4], row[5], R);
        ac[0][0] = (k == 0) ? R[0] : ((k == 1) ? R[1] : R[2]);
        ac[0][1] = (k == 0) ? R[3] : ((k == 1) ? R[4] : R[5]);
        ac[0][2] = (k == 0) ? R[6] : ((k == 1) ? R[7] : R[8]);
        pp[0] = off[k] + row[k];

        #pragma unroll
        for (int s = 1; s <= 12; ++s) {
            const int i  = OFF_IDX[s];
            const int pa = PAR[s];
            const int col = 3*i + 3;             // in [6,47] for s<=12
            float L[9];
            rodrigues(row[col], row[col+1], row[col+2], L);
            const float o0 = off[3*i], o1 = off[3*i+1], o2 = off[3*i+2];
            pp[s] = o0*ac[pa][0] + o1*ac[pa][1] + o2*ac[pa][2] + pp[pa];
            ac[s][0] = L[0]*ac[pa][0] + L[1]*ac[pa][1] + L[2]*ac[pa][2];
            ac[s][1] = L[3]*ac[pa][0] + L[4]*ac[pa][1] + L[5]*ac[pa][2];
            ac[s][2] = L[6]*ac[pa][0] + L[7]*ac[pa][1] + L[8]*ac[pa][2];
        }
    }
    __syncthreads();                             // chunk A input now dead

    // ---- flush half A: pos slots 0..12 (out cols 0..38) ----
    #pragma unroll
    for (int s = 0; s <= 12; ++s)
        buf[r*LSTR + 3*s + k] = pp[s];           // banks 17r+const: 2-way, free
    __syncthreads();
    {
        float* oA = out + (long long)row0 * OUTW;
        #pragma unroll
        for (int j = 0; j < 13; ++j) {           // 13*192 = 2496 = 64*39 exact
            int m = t + j*TPB;
            int rr = m / 39;                     // magic mul
            int cc = m - rr*39;
            oA[rr*OUTW + cc] = buf[rr*LSTR + cc];
        }
    }
    __syncthreads();                             // half-A reads done

    // ---- stage chunk B: floats [48..96) of each row ----
    #pragma unroll
    for (int j = 0; j < 16; ++j) {
        int rr = r0 + 4*j;
        buf[rr*LSTR + c0] = x[(long long)(row0 + rr)*XDIM + CHW + c0];
    }
    __syncthreads();

    // ---- compute slots 13..25 (inputs wholly in chunk B) ----
    {
        const float* row = &buf[r*LSTR];
        #pragma unroll
        for (int s = 13; s < NJ; ++s) {
            const int i  = OFF_IDX[s];
            const int pa = PAR[s];
            const int col = 3*i + 3 - CHW;       // in [0,45] for s>=13
            float L[9];
            rodrigues(row[col], row[col+1], row[col+2], L);
            const float o0 = off[3*i], o1 = off[3*i+1], o2 = off[3*i+2];
            pp[s] = o0*ac[pa][0] + o1*ac[pa][1] + o2*ac[pa][2] + pp[pa];
            ac[s][0] = L[0]*ac[pa][0] + L[1]*ac[pa][1] + L[2]*ac[pa][2];
            ac[s][1] = L[3]*ac[pa][0] + L[4]*ac[pa][1] + L[5]*ac[pa][2];
            ac[s][2] = L[6]*ac[pa][0] + L[7]*ac[pa][1] + L[8]*ac[pa][2];
        }
    }
    __syncthreads();                             // chunk B input now dead

    // ---- flush half B: pos slots 13..25 (out cols 39..77) ----
    #pragma unroll
    for (int s = 13; s < NJ; ++s)
        buf[r*LSTR + 3*(s-13) + k] = pp[s];
    __syncthreads();
    {
        float* oB = out + (long long)row0 * OUTW + 39;
        #pragma unroll
        for (int j = 0; j < 13; ++j) {
            int m = t + j*TPB;
            int rr = m / 39;
            int cc = m - rr*39;
            oB[rr*OUTW + cc] = buf[rr*LSTR + cc];
        }
    }
}

extern "C" void kernel_launch(void* const* d_in, const int* in_sizes, int n_in,
                              void* d_out, int out_size, void* d_ws, size_t ws_size,
                              hipStream_t stream) {
    const float* x   = (const float*)d_in[0];
    const float* off = (const float*)d_in[1];
    float* out = (float*)d_out;
    const int B = in_sizes[0] / XDIM;      // 262144
    const int grid = B / ROWS;             // 4096
    skel_fk<<<grid, TPB, 0, stream>>>(x, off, out);
}

// Round 7
// 48.486 us; speedup vs baseline: 1.5305x; 1.5305x over previous
//
#include <hip/hip_runtime.h>

#define ROWS 64      // rows per block
#define TPB  192     // 3 waves: wave k owns matrix column k for all 64 rows
#define XDIM 99
#define NJ   26
#define LSTR 49      // input-stage LDS row stride (odd -> 2-way max on reads, free)
#define CHW  48      // staged chunk width (2 chunks cover floats 0..95)
#define SSTR 79      // flush-scratch row stride (15 ≡ 79 mod 32, coprime -> conflict-free)
#define OUTW 78      // output floats per row

__device__ __forceinline__ void rodrigues(float ax, float ay, float az, float* R) {
    const float EPS = 1.1920928955078125e-07f;   // np.finfo(np.float32).eps
    float t = sqrtf(ax*ax + ay*ay + az*az);
    float inv = 1.0f / (t + EPS);
    float r0 = ax*inv, r1 = ay*inv, r2 = az*inv;
    float s = __sinf(t);
    float c = __cosf(t);
    float omc = 1.0f - c;
    float r00 = r0*r0, r11 = r1*r1, r22 = r2*r2;
    float r01 = r0*r1, r02 = r0*r2, r12 = r1*r2;
    R[0] = 1.0f - omc*(r11 + r22);
    R[1] = -s*r2 + omc*r01;
    R[2] =  s*r1 + omc*r02;
    R[3] =  s*r2 + omc*r01;
    R[4] = 1.0f - omc*(r00 + r22);
    R[5] = -s*r0 + omc*r12;
    R[6] = -s*r1 + omc*r02;
    R[7] =  s*r0 + omc*r12;
    R[8] = 1.0f - omc*(r00 + r11);
}

__global__ __launch_bounds__(TPB, 8) void skel_fk(const float* __restrict__ x,
                                                  const float* __restrict__ off,
                                                  float* __restrict__ out) {
    __shared__ float buf[ROWS * LSTR];           // 12544 B -> 10 blocks/CU = 30 waves/CU
    const int t = threadIdx.x;
    const int row0 = blockIdx.x * ROWS;
    const int r = t & 63;                        // row owned in compute/flush phases
    const int k = t >> 6;                        // matrix column (wave-uniform)

    // staging decomposition: 192 = 4*48 -> thread t loads column c0 of rows r0+4j
    const int c0 = t % CHW;
    const int r0 = t / CHW;

    // slot tables (slot 0 = hip, slots 1..25 follow ORDER)
    constexpr int OFF_IDX[NJ] = {0,1,2,3,4,6,7,8,9,11,12,13,14,15,16,17,18,19,20,22,24,25,26,27,28,30};
    constexpr int PAR[NJ]     = {-1,0,1,2,3,0,5,6,7,0,9,10,11,12,10,14,15,16,17,17,10,20,21,22,23,23};

    float ac[NJ][3];   // column k of ang[slot]; compile-time indices -> registers
    float pp[NJ];      // component k of pos[slot]; ALL kept live until flush

    // ---- stage chunk A: floats [0..48) of each row ----
    #pragma unroll
    for (int j = 0; j < 16; ++j) {
        int rr = r0 + 4*j;
        buf[rr*LSTR + c0] = x[(long long)(row0 + rr)*XDIM + c0];
    }
    __syncthreads();

    // ---- compute slots 0..12 (inputs wholly in chunk A; no LDS writes) ----
    {
        const float* row = &buf[r*LSTR];
        float R[9];
        rodrigues(row[3], row[4], row[5], R);
        ac[0][0] = (k == 0) ? R[0] : ((k == 1) ? R[1] : R[2]);
        ac[0][1] = (k == 0) ? R[3] : ((k == 1) ? R[4] : R[5]);
        ac[0][2] = (k == 0) ? R[6] : ((k == 1) ? R[7] : R[8]);
        pp[0] = off[k] + row[k];

        #pragma unroll
        for (int s = 1; s <= 12; ++s) {
            const int i  = OFF_IDX[s];
            const int pa = PAR[s];
            const int col = 3*i + 3;             // in [6,47]
            float L[9];
            rodrigues(row[col], row[col+1], row[col+2], L);
            const float o0 = off[3*i], o1 = off[3*i+1], o2 = off[3*i+2];
            pp[s] = o0*ac[pa][0] + o1*ac[pa][1] + o2*ac[pa][2] + pp[pa];
            ac[s][0] = L[0]*ac[pa][0] + L[1]*ac[pa][1] + L[2]*ac[pa][2];
            ac[s][1] = L[3]*ac[pa][0] + L[4]*ac[pa][1] + L[5]*ac[pa][2];
            ac[s][2] = L[6]*ac[pa][0] + L[7]*ac[pa][1] + L[8]*ac[pa][2];
        }
    }
    __syncthreads();                             // chunk A reads done everywhere

    // ---- stage chunk B: floats [48..96) of each row ----
    #pragma unroll
    for (int j = 0; j < 16; ++j) {
        int rr = r0 + 4*j;
        buf[rr*LSTR + c0] = x[(long long)(row0 + rr)*XDIM + CHW + c0];
    }
    __syncthreads();

    // ---- compute slots 13..25 (inputs wholly in chunk B) ----
    {
        const float* row = &buf[r*LSTR];
        #pragma unroll
        for (int s = 13; s < NJ; ++s) {
            const int i  = OFF_IDX[s];
            const int pa = PAR[s];
            const int col = 3*i + 3 - CHW;       // in [0,45]
            float L[9];
            rodrigues(row[col], row[col+1], row[col+2], L);
            const float o0 = off[3*i], o1 = off[3*i+1], o2 = off[3*i+2];
            pp[s] = o0*ac[pa][0] + o1*ac[pa][1] + o2*ac[pa][2] + pp[pa];
            ac[s][0] = L[0]*ac[pa][0] + L[1]*ac[pa][1] + L[2]*ac[pa][2];
            ac[s][1] = L[3]*ac[pa][0] + L[4]*ac[pa][1] + L[5]*ac[pa][2];
            ac[s][2] = L[6]*ac[pa][0] + L[7]*ac[pa][1] + L[8]*ac[pa][2];
        }
    }
    __syncthreads();                             // chunk B reads done; buf now dead

    // ---- flush: two 32-row groups through reused buf (stride SSTR=79).
    //      Each group writes out dwords [2496g, 2496(g+1)) -- 9984 B, 64B-aligned,
    //      full cache lines, each line touched exactly once. ----
    float* oblk = out + (long long)row0 * OUTW;
    #pragma unroll
    for (int g = 0; g < 2; ++g) {
        if (g) __syncthreads();                  // previous group's reads done
        if ((r >> 5) == g) {
            float* srow = &buf[(r & 31) * SSTR];
            #pragma unroll
            for (int s = 0; s < NJ; ++s)
                srow[3*s + k] = pp[s];           // banks 15*(r&31)+const: all distinct
        }
        __syncthreads();
        #pragma unroll
        for (int j = 0; j < 13; ++j) {           // 13*192 = 2496 = 32*78 exact
            int m = t + j*TPB;
            int rr = m / OUTW;                   // const divisor -> magic mul
            int cc = m - rr*OUTW;
            oblk[g*2496 + m] = buf[rr*SSTR + cc];
        }
    }
}

extern "C" void kernel_launch(void* const* d_in, const int* in_sizes, int n_in,
                              void* d_out, int out_size, void* d_ws, size_t ws_size,
                              hipStream_t stream) {
    const float* x   = (const float*)d_in[0];
    const float* off = (const float*)d_in[1];
    float* out = (float*)d_out;
    const int B = in_sizes[0] / XDIM;      // 262144
    const int grid = B / ROWS;             // 4096
    skel_fk<<<grid, TPB, 0, stream>>>(x, off, out);
}